// Round 7
// baseline (253.231 us; speedup 1.0000x reference)
//
#include <hip/hip_runtime.h>

// FM_FTRL == two unit-lower-triangular solves:
//   alpha_i = -2eta*(x_0.x_i - q0*q_i)  (closed form, K_A=1; alpha_0 = 1)
//   (I+Lh)s = r, Lh[i,j] = 2eta*(x_j.x_i) j<i
//   r_i = 2*(alpha_i^2*T0 - b_i) (i>=1), r_0 = 2*(s0 + T0 - b_0)
//   preds = s/2 + b ;  K_B=2: s ~= r - L r + L^2 r
// R6 postmortem: LDS>64KB => 1 block/CU (R2/R3 56.8KB->65% occ vs R5/R6
// 117/70.6KB->33/38%). Warm runs L3-resident (5MB) yet same dur -> the
// column-gather (64B segments x 1024 rows) is the limiter, paid 3x.
// R7: CC=8, all kernels <64KB LDS (2 blocks/CU); k_gram gathers ONCE and
// dumps chunk to Xc[c][e][j] (contiguous, coalesced); k_terms read columns
// as 2 coalesced float4s, all-register sweep + shfl butterflies (LDS ~1KB).
// Runtime ws_size check (needs ~93MB) with LDS-stage fallback.

#define NN 20000
#define CC 8
#define NCH 2500
#define ETA2 2e-5f
#define XST 1032  // xl row stride (floats)

// ws float offsets
#define OFF_GRAM 0L        // 2500 x 28 packed strict-lower
#define OFF_Z    70016L    // 2500 x 1024; Zr->S1->Z1->S2 in place
#define OFF_SCLP 2630016L  // [0..31] T0 partials, [32] s0
#define OFF_ACC  2630080L
#define OFF_TV   2650112L
#define OFF_X0   2670144L  // x0 column, contiguous (1024)
#define OFF_XC   2671168L  // Xc[c][e][j]: 2500*1024*8 floats (81.9 MB)
#define WS_NEED_BYTES ((size_t)(OFF_XC + 20480000L) * 4)

// ---------------- k0: T0/s0 partials + x0 stash + b-copy -------------------
__global__ __launch_bounds__(1024) void k_init(
    const float* __restrict__ At, const float* __restrict__ bvec,
    const float* __restrict__ w1, const float* __restrict__ W2,
    float* __restrict__ out, float* __restrict__ scalp,
    float* __restrict__ x0ws) {
  __shared__ float x0s[1024];
  __shared__ float part[16];
  const int bid = blockIdx.x, t = threadIdx.x;
  const int wid = t >> 6, lane = t & 63;

  if (bid < 32) {  // T0 partial over 16 W2 rows
    x0s[t] = (t < 1023) ? At[(long)t * NN] : 0.f;
    __syncthreads();
    const int row = bid * 16 + wid;
    float p = 0.f;
#pragma unroll
    for (int k = 0; k < 16; ++k) {
      const int ci = k * 64 + lane;
      if (ci < 1023) p = fmaf(W2[(long)row * 1023 + ci], x0s[ci], p);
    }
#pragma unroll
    for (int o = 32; o > 0; o >>= 1) p += __shfl_down(p, o);
    if (lane == 0) part[wid] = p * p;
    __syncthreads();
    if (t == 0) {
      float s = 0.f;
#pragma unroll
      for (int k = 0; k < 16; ++k) s += part[k];
      scalp[bid] = s;
    }
  } else if (bid == 32) {  // s0 = w1 . x0 ; stash x0 contiguously
    const float xv = At[(long)t * NN];
    x0ws[t] = xv;
    float p = w1[t] * xv;
#pragma unroll
    for (int o = 32; o > 0; o >>= 1) p += __shfl_down(p, o);
    if (lane == 0) part[wid] = p;
    __syncthreads();
    if (t == 0) {
      float s = 0.f;
#pragma unroll
      for (int k = 0; k < 16; ++k) s += part[k];
      scalp[32] = s;
    }
  } else {  // b-copy: 20 blocks x 1000
    const int i = (bid - 33) * 1000 + t;
    if (t < 1000) out[NN + i] = bvec[i];
  }
}

// Stage: f4 index g in [0,2048): e=g>>1, q=g&1; src At[e][i0+4q..+3];
// dst xl[(4q+j)*XST + e] (banks: 2-way max, free).
#define STAGE8(g, xl)                                               \
  {                                                                 \
    const int e_ = (g) >> 1, q_ = (g) & 1;                          \
    const float4 v_ =                                               \
        *(const float4*)(At + (long)e_ * NN + i0 + 4 * q_);         \
    xl[(4 * q_ + 0) * XST + e_] = v_.x;                             \
    xl[(4 * q_ + 1) * XST + e_] = v_.y;                             \
    xl[(4 * q_ + 2) * XST + e_] = v_.z;                             \
    xl[(4 * q_ + 3) * XST + e_] = v_.w;                             \
  }

// ---------------- k1: chunk Gram + alpha + r + Zr + Xc dump ----------------
// pair-threads: t<896: pi=t>>5 (28 strict-lower pairs), band=t&31
//   (e-slices f4 = band+32k, lane-consecutive -> conflict-free).
// u-threads: t>=896: uj=(t-896)>>4, b16=(t-896)&15 (16-lane groups).
struct GramSh {
  __align__(16) float xl[CC * XST];  // 33,024 B
  __align__(16) float x0s[1024];     // 4,096 B
  float usum[CC];
  float rs[CC];
  float sc[2];
};
static_assert(sizeof(GramSh) <= 64 * 1024, "LDS must stay under 64KB");

__global__ __launch_bounds__(1024, 4) void k_gram(
    const float* __restrict__ At, const float* __restrict__ bvec,
    const float* __restrict__ x0g, float* __restrict__ gram,
    float* __restrict__ Zr, const float* __restrict__ scalp,
    float* __restrict__ acc, float* __restrict__ Xc, const int writeXc) {
  __shared__ GramSh sh;
  const int c = blockIdx.x, t = threadIdx.x;
  const long i0 = (long)c * CC;

  sh.x0s[t] = x0g[t];
  if (t == 0) {
    float T = 0.f;
#pragma unroll
    for (int k = 0; k < 32; ++k) T += scalp[k];
    sh.sc[0] = T;
    sh.sc[1] = scalp[32];
  }

  STAGE8(t, sh.xl);
  STAGE8(1024 + t, sh.xl);
  __syncthreads();

  if (t < 896) {  // gram pairs
    const int pi = t >> 5, band = t & 31;
    int i = 1;
    while ((i + 1) * i / 2 <= pi) ++i;
    const int j = pi - i * (i - 1) / 2;
    float p = 0.f;
#pragma unroll
    for (int k = 0; k < 8; ++k) {
      const int ef = (band + 32 * k) * 4;
      const float4 A = *(const float4*)&sh.xl[i * XST + ef];
      const float4 B = *(const float4*)&sh.xl[j * XST + ef];
      p = fmaf(A.x, B.x, p);
      p = fmaf(A.y, B.y, p);
      p = fmaf(A.z, B.z, p);
      p = fmaf(A.w, B.w, p);
    }
#pragma unroll
    for (int off = 16; off >= 1; off >>= 1) p += __shfl_xor(p, off);
    if (band == 0) gram[(long)c * 28 + pi] = p;
  } else {  // u_j = x0 . x_j
    const int uz = t - 896, uj = uz >> 4, b16 = uz & 15;
    float p = 0.f;
#pragma unroll
    for (int k = 0; k < 16; ++k) {
      const int ef = (b16 + 16 * k) * 4;
      const float4 X = *(const float4*)&sh.xl[uj * XST + ef];
      const float4 X0 = *(const float4*)&sh.x0s[ef];
      p = fmaf(X.x, X0.x, p);
      p = fmaf(X.y, X0.y, p);
      p = fmaf(X.z, X0.z, p);
      p = fmaf(X.w, X0.w, p);
    }
#pragma unroll
    for (int off = 8; off >= 1; off >>= 1) p += __shfl_xor(p, off);
    if (b16 == 0) sh.usum[uj] = p;
  }
  __syncthreads();

  // alpha (closed form) -> r
  if (t < CC) {
    const long gi = i0 + t;
    const float uu = sh.usum[t];
    const float qi = sh.xl[t * XST + 1023];
    const float q0 = sh.x0s[1023];
    const float al = (gi == 0) ? 1.f : -ETA2 * (uu - q0 * qi);
    const float T0 = sh.sc[0], s0v = sh.sc[1];
    const float bv = bvec[gi];
    float r = 2.f * fmaf(al * al, T0, -bv);
    if (gi == 0) r = 2.f * (s0v + T0 - bv);
    sh.rs[t] = r;
    acc[gi] = r;
  }
  __syncthreads();

  // column regs -> Zr (+ contiguous Xc dump)
  {
    float x[CC];
#pragma unroll
    for (int j = 0; j < CC; ++j) x[j] = sh.xl[j * XST + t];
    float z = 0.f;
#pragma unroll
    for (int j = 0; j < CC; ++j) z = fmaf(sh.rs[j], x[j], z);
    Zr[(long)c * 1024 + t] = z;
    if (writeXc) {
      float* dst = Xc + ((long)c * 1024 + t) * CC;
      *(float4*)dst = make_float4(x[0], x[1], x[2], x[3]);
      *(float4*)(dst + 4) = make_float4(x[4], x[5], x[6], x[7]);
    }
  }
}

// ---------------- scan: IN PLACE Z -> exclusive prefix S -------------------
// 32 blocks x (32 c-groups x 32 e-lanes); chain 79, loads 8-batched.
__global__ __launch_bounds__(1024) void k_scan(float* __restrict__ Z) {
  __shared__ float gsum[32][33];
  const int t = threadIdx.x;
  const int ei = t & 31, ci = t >> 5;
  const int e = blockIdx.x * 32 + ei;
  const int c0 = ci * 79;
  const int c1 = (c0 + 79 < NCH) ? c0 + 79 : NCH;

  float s = 0.f;
  for (int base = c0; base < c1; base += 8) {
    float v[8];
#pragma unroll
    for (int k = 0; k < 8; ++k) {
      const int cc = base + k;
      v[k] = (cc < c1) ? Z[(long)cc * 1024 + e] : 0.f;
    }
#pragma unroll
    for (int k = 0; k < 8; ++k) s += v[k];
  }
  gsum[ci][ei] = s;
  __syncthreads();

  float off = 0.f;
#pragma unroll
  for (int k = 0; k < 31; ++k)
    if (k < ci) off += gsum[k][ei];

  s = off;
  for (int base = c0; base < c1; base += 8) {
    float v[8];
#pragma unroll
    for (int k = 0; k < 8; ++k) {
      const int cc = base + k;
      v[k] = (cc < c1) ? Z[(long)cc * 1024 + e] : 0.f;
    }
#pragma unroll
    for (int k = 0; k < 8; ++k) {
      const int cc = base + k;
      if (cc < c1) Z[(long)cc * 1024 + e] = s;  // in place: v read first
      s += v[k];
    }
  }
}

// ---------------- term: w = -(L v) ----------------------------------------
// TR=true : column from Xc (2 coalesced f4), all-register sweep, LDS ~1KB.
// TR=false: LDS-stage fallback (gather from At).
// S and Z1 alias one buffer: row c read (sv) before row c written.
// LAST=false: v=r(acc), w=t1; tvec=t1, acc=r+t1, Z1.
// LAST=true : v=t1(tvec), w=t2; out = 0.5*(acc+t2) + b.
template <bool TR, bool LAST>
__global__ __launch_bounds__(1024, 4) void k_term(
    const float* __restrict__ At, const float* __restrict__ bvec,
    const float* __restrict__ gram, const float* __restrict__ S,
    float* __restrict__ Z1, float* __restrict__ acc, float* __restrict__ tvec,
    float* __restrict__ out, const float* __restrict__ Xc) {
  __shared__ float red[16][CC];
  __shared__ float vvs[CC], wvs[CC];
  __shared__ float xl[TR ? 16 : CC * XST];
  const int c = blockIdx.x, t = threadIdx.x;
  const int wid = t >> 6, lane = t & 63;
  const long i0 = (long)c * CC;

  if (t < CC) vvs[t] = LAST ? tvec[i0 + t] : acc[i0 + t];

  float x[CC];
  if (TR) {
    const float* src = Xc + ((long)c * 1024 + t) * CC;
    const float4 a = *(const float4*)src;
    const float4 b4 = *(const float4*)(src + 4);
    x[0] = a.x; x[1] = a.y; x[2] = a.z; x[3] = a.w;
    x[4] = b4.x; x[5] = b4.y; x[6] = b4.z; x[7] = b4.w;
  } else {
    STAGE8(t, xl);
    STAGE8(1024 + t, xl);
    __syncthreads();
#pragma unroll
    for (int j = 0; j < CC; ++j) x[j] = xl[j * XST + t];
  }

  const float sv = S[(long)c * 1024 + t];
  float p[CC];
#pragma unroll
  for (int j = 0; j < CC; ++j) p[j] = x[j] * sv;
#pragma unroll
  for (int off = 32; off >= 1; off >>= 1)
#pragma unroll
    for (int j = 0; j < CC; ++j) p[j] += __shfl_xor(p[j], off);
  if (lane == 0)
#pragma unroll
    for (int j = 0; j < CC; ++j) red[wid][j] = p[j];
  __syncthreads();

  if (t < CC) {
    const int i = t;
    float dot = 0.f;
#pragma unroll
    for (int k = 0; k < 16; ++k) dot += red[k][i];
    const float* grow = gram + (long)c * 28 + i * (i - 1) / 2;
    float g = 0.f;
#pragma unroll
    for (int j = 0; j < CC - 1; ++j)
      if (j < i) g = fmaf(grow[j], vvs[j], g);
    const float w = -ETA2 * (dot + g);
    if (LAST) {
      out[i0 + i] = fmaf(0.5f, acc[i0 + i] + w, bvec[i0 + i]);
    } else {
      wvs[i] = w;
      tvec[i0 + i] = w;
      acc[i0 + i] += w;
    }
  }
  if (!LAST) {
    __syncthreads();
    float z = 0.f;
#pragma unroll
    for (int j = 0; j < CC; ++j) z = fmaf(wvs[j], x[j], z);
    Z1[(long)c * 1024 + t] = z;
  }
}

extern "C" void kernel_launch(void* const* d_in, const int* in_sizes, int n_in,
                              void* d_out, int out_size, void* d_ws,
                              size_t ws_size, hipStream_t stream) {
  const float* At = (const float*)d_in[0];  // (1024, 20000) row-major
  const float* b  = (const float*)d_in[1];
  const float* w1 = (const float*)d_in[2];
  const float* W2 = (const float*)d_in[3];  // (512, 1023) row-major
  float* out = (float*)d_out;
  float* ws = (float*)d_ws;

  float* gram  = ws + OFF_GRAM;
  float* Zsh   = ws + OFF_Z;  // Zr -> S1 -> Z1 -> S2 (single buffer)
  float* scalp = ws + OFF_SCLP;
  float* acc   = ws + OFF_ACC;
  float* tvec  = ws + OFF_TV;
  float* x0ws  = ws + OFF_X0;
  float* Xc    = ws + OFF_XC;

  const int bigws = (ws_size >= WS_NEED_BYTES) ? 1 : 0;

  k_init<<<dim3(53), dim3(1024), 0, stream>>>(At, b, w1, W2, out, scalp, x0ws);
  k_gram<<<dim3(NCH), dim3(1024), 0, stream>>>(At, b, x0ws, gram, Zsh, scalp,
                                               acc, Xc, bigws);
  k_scan<<<dim3(32), dim3(1024), 0, stream>>>(Zsh);
  if (bigws) {
    k_term<true, false><<<dim3(NCH), dim3(1024), 0, stream>>>(
        At, b, gram, Zsh, Zsh, acc, tvec, out, Xc);
    k_scan<<<dim3(32), dim3(1024), 0, stream>>>(Zsh);
    k_term<true, true><<<dim3(NCH), dim3(1024), 0, stream>>>(
        At, b, gram, Zsh, Zsh, acc, tvec, out, Xc);
  } else {
    k_term<false, false><<<dim3(NCH), dim3(1024), 0, stream>>>(
        At, b, gram, Zsh, Zsh, acc, tvec, out, Xc);
    k_scan<<<dim3(32), dim3(1024), 0, stream>>>(Zsh);
    k_term<false, true><<<dim3(NCH), dim3(1024), 0, stream>>>(
        At, b, gram, Zsh, Zsh, acc, tvec, out, Xc);
  }
}

// Round 8
// 233.266 us; speedup vs baseline: 1.0856x; 1.0856x over previous
//
#include <hip/hip_runtime.h>

// FM_FTRL == two unit-lower-triangular solves:
//   alpha_i = -2eta*(x_0.x_i - q0*q_i)  (closed form, K_A=1; alpha_0 = 1)
//   (I+Lh)s = r, Lh[i,j] = 2eta*(x_j.x_i) j<i
//   r_i = 2*(alpha_i^2*T0 - b_i) (i>=1), r_0 = 2*(s0 + T0 - b_0)
//   preds = s/2 + b ;  K_B=2: s ~= r - L r + L^2 r
// Ledger: CC=16 is byte-exact (64B rows = cache lines; R6 FETCH=80MB exact;
// CC=8 doubled fetch, R7). LDS<=64KB is the 2-blocks/CU boundary (R3 56.8KB
// ->66% occ; R5/R6 70-117KB->33-38%). R8: CC=16 with LDS = EXACTLY 64KB:
// x0 from global, u+alpha fused in wave 15 (shfl reduce, no usum/rs LDS),
// r broadcast via xl-overwrite after reg-preload, gram via 64-lane butterfly,
// terms shuffle-based with xl reused as scratch after preload.

#define NN 20000
#define CC 16
#define NCH 1250
#define ETA2 2e-5f

// ws float offsets (~5.9 MB)
#define OFF_GRAM 0L        // 1250 x 120 packed strict-lower
#define OFF_Z    150016L   // 1250 x 1024; Zr->S1->Z1->S2 in place
#define OFF_SCLP 1430016L  // [0..31] T0 partials, [32] s0
#define OFF_ACC  1430080L
#define OFF_TV   1450080L
#define OFF_X0   1470080L  // x0 column, contiguous (1024)

// ---------------- k0: T0/s0 partials + x0 stash + b-copy -------------------
__global__ __launch_bounds__(1024) void k_init(
    const float* __restrict__ At, const float* __restrict__ bvec,
    const float* __restrict__ w1, const float* __restrict__ W2,
    float* __restrict__ out, float* __restrict__ scalp,
    float* __restrict__ x0ws) {
  __shared__ float x0s[1024];
  __shared__ float part[16];
  const int bid = blockIdx.x, t = threadIdx.x;
  const int wid = t >> 6, lane = t & 63;

  if (bid < 32) {  // T0 partial over 16 W2 rows
    x0s[t] = (t < 1023) ? At[(long)t * NN] : 0.f;
    __syncthreads();
    const int row = bid * 16 + wid;
    float p = 0.f;
#pragma unroll
    for (int k = 0; k < 16; ++k) {
      const int ci = k * 64 + lane;
      if (ci < 1023) p = fmaf(W2[(long)row * 1023 + ci], x0s[ci], p);
    }
#pragma unroll
    for (int o = 32; o > 0; o >>= 1) p += __shfl_down(p, o);
    if (lane == 0) part[wid] = p * p;
    __syncthreads();
    if (t == 0) {
      float s = 0.f;
#pragma unroll
      for (int k = 0; k < 16; ++k) s += part[k];
      scalp[bid] = s;
    }
  } else if (bid == 32) {  // s0 = w1 . x0 ; stash x0 contiguously
    const float xv = At[(long)t * NN];
    x0ws[t] = xv;
    float p = w1[t] * xv;
#pragma unroll
    for (int o = 32; o > 0; o >>= 1) p += __shfl_down(p, o);
    if (lane == 0) part[wid] = p;
    __syncthreads();
    if (t == 0) {
      float s = 0.f;
#pragma unroll
      for (int k = 0; k < 16; ++k) s += part[k];
      scalp[32] = s;
    }
  } else {  // b-copy: 20 blocks x 1000
    const int i = (bid - 33) * 1000 + t;
    if (t < 1000) out[NN + i] = bvec[i];
  }
}

// Stage: f4 index g in [0,4096): e=g>>2, q=g&3; src At[e][i0+4q..] = one
// 64B line per e (byte-exact); dst transposed xl[(4q+j)<<10 | e].
#define STAGE16(g)                                                      \
  {                                                                     \
    const int e_ = (g) >> 2, q_ = (g) & 3;                              \
    const float4 v_ =                                                   \
        *(const float4*)(At + (long)e_ * NN + i0 + 4 * q_);             \
    xl[((4 * q_ + 0) << 10) | e_] = v_.x;                               \
    xl[((4 * q_ + 1) << 10) | e_] = v_.y;                               \
    xl[((4 * q_ + 2) << 10) | e_] = v_.z;                               \
    xl[((4 * q_ + 3) << 10) | e_] = v_.w;                               \
  }

// ---------------- k1: chunk Gram + alpha + r + Zr --------------------------
// waves 0..9: lower-tri 4x4 tile wv x 64 e-lanes (b128 reads: lane-
//   consecutive 16B -> conflict-free); butterfly over 64 lanes; lane0
//   writes packed gram.
// wave 15: u (16 j x 4 e-groups, lane-staggered) + alpha/r on lanes 0..15.
__global__ __launch_bounds__(1024, 4) void k_gram(
    const float* __restrict__ At, const float* __restrict__ bvec,
    const float* __restrict__ x0g, float* __restrict__ gram,
    float* __restrict__ Zr, const float* __restrict__ scalp,
    float* __restrict__ acc) {
  __shared__ float xl[16384];  // 65,536 B EXACT — nothing else in LDS
  const int c = blockIdx.x, t = threadIdx.x;
  const long i0 = (long)c * CC;
  const int wv = t >> 6, lane = t & 63;

  STAGE16(t);
  STAGE16(1024 + t);
  STAGE16(2048 + t);
  STAGE16(3072 + t);
  __syncthreads();

  float r_val = 0.f;
  bool is_alpha = false;

  if (wv < 10) {  // gram tile (a, bb)
    int a = 0, rr = wv;
    while (rr > a) { rr -= ++a; }
    const int bb = rr;
    float ac[16];
#pragma unroll
    for (int k = 0; k < 16; ++k) ac[k] = 0.f;
#pragma unroll
    for (int k = 0; k < 4; ++k) {
      const int f4 = 4 * (lane + 64 * k);
      const float4 A0 = *(const float4*)&xl[((4 * a + 0) << 10) | f4];
      const float4 A1 = *(const float4*)&xl[((4 * a + 1) << 10) | f4];
      const float4 A2 = *(const float4*)&xl[((4 * a + 2) << 10) | f4];
      const float4 A3 = *(const float4*)&xl[((4 * a + 3) << 10) | f4];
      const float4 B0 = *(const float4*)&xl[((4 * bb + 0) << 10) | f4];
      const float4 B1 = *(const float4*)&xl[((4 * bb + 1) << 10) | f4];
      const float4 B2 = *(const float4*)&xl[((4 * bb + 2) << 10) | f4];
      const float4 B3 = *(const float4*)&xl[((4 * bb + 3) << 10) | f4];
      const float4 RA[4] = {A0, A1, A2, A3};
      const float4 RB[4] = {B0, B1, B2, B3};
#pragma unroll
      for (int r_ = 0; r_ < 4; ++r_)
#pragma unroll
        for (int s_ = 0; s_ < 4; ++s_) {
          ac[r_ * 4 + s_] = fmaf(RA[r_].x, RB[s_].x, ac[r_ * 4 + s_]);
          ac[r_ * 4 + s_] = fmaf(RA[r_].y, RB[s_].y, ac[r_ * 4 + s_]);
          ac[r_ * 4 + s_] = fmaf(RA[r_].z, RB[s_].z, ac[r_ * 4 + s_]);
          ac[r_ * 4 + s_] = fmaf(RA[r_].w, RB[s_].w, ac[r_ * 4 + s_]);
        }
    }
#pragma unroll
    for (int off = 32; off >= 1; off >>= 1)
#pragma unroll
      for (int k = 0; k < 16; ++k) ac[k] += __shfl_xor(ac[k], off);
    if (lane == 0) {
      float* gp = gram + (long)c * 120;
#pragma unroll
      for (int r_ = 0; r_ < 4; ++r_) {
        const int row = 4 * a + r_;
        const int base = row * (row - 1) / 2;
#pragma unroll
        for (int s_ = 0; s_ < 4; ++s_) {
          const int col = 4 * bb + s_;
          if (col < row) gp[base + col] = ac[r_ * 4 + s_];
        }
      }
    }
  } else if (wv == 15) {  // u + alpha
    const int uj = lane & 15, ug = lane >> 4;
    float p = 0.f;
#pragma unroll 8
    for (int k = 0; k < 64; ++k) {
      const int f = ug * 64 + ((k + uj) & 63);
      const float4 xv = *(const float4*)&xl[(uj << 10) | (4 * f)];
      const float4 x0 = *(const float4*)(x0g + 4 * f);
      p = fmaf(xv.x, x0.x, p);
      p = fmaf(xv.y, x0.y, p);
      p = fmaf(xv.z, x0.z, p);
      p = fmaf(xv.w, x0.w, p);
    }
    p += __shfl_xor(p, 16);
    p += __shfl_xor(p, 32);
    if (lane < 16) {
      const long gi = i0 + lane;
      const float qi = xl[(lane << 10) | 1023];
      const float q0 = x0g[1023];
      float T0 = 0.f;
#pragma unroll
      for (int k = 0; k < 32; ++k) T0 += scalp[k];
      const float s0v = scalp[32];
      const float bv = bvec[gi];
      const float al = (gi == 0) ? 1.f : -ETA2 * (p - q0 * qi);
      r_val = 2.f * fmaf(al * al, T0, -bv);
      if (gi == 0) r_val = 2.f * (s0v + T0 - bv);
      acc[gi] = r_val;
      is_alpha = true;
    }
  }

  // preload x-column into regs (conflict-free: lane-consecutive scalars)
  float x[16];
#pragma unroll
  for (int j = 0; j < 16; ++j) x[j] = xl[(j << 10) | t];
  __syncthreads();

  if (is_alpha) xl[lane] = r_val;  // overwrite slot owners hold x in regs
  __syncthreads();

  float z = 0.f;
#pragma unroll
  for (int j = 0; j < 16; ++j) z = fmaf(xl[j], x[j], z);  // broadcast reads
  Zr[(long)c * 1024 + t] = z;
}

// ---------------- scan: IN PLACE Z -> exclusive prefix S -------------------
// 32 blocks x (32 c-groups x 32 e-lanes); chain 40, loads 8-batched.
__global__ __launch_bounds__(1024) void k_scan(float* __restrict__ Z) {
  __shared__ float gsum[32][33];
  const int t = threadIdx.x;
  const int ei = t & 31, ci = t >> 5;
  const int e = blockIdx.x * 32 + ei;
  const int c0 = ci * 40;
  const int c1 = (c0 + 40 < NCH) ? c0 + 40 : NCH;

  float s = 0.f;
  for (int base = c0; base < c1; base += 8) {
    float v[8];
#pragma unroll
    for (int k = 0; k < 8; ++k) {
      const int cc = base + k;
      v[k] = (cc < c1) ? Z[(long)cc * 1024 + e] : 0.f;
    }
#pragma unroll
    for (int k = 0; k < 8; ++k) s += v[k];
  }
  gsum[ci][ei] = s;
  __syncthreads();

  float off = 0.f;
#pragma unroll
  for (int k = 0; k < 31; ++k)
    if (k < ci) off += gsum[k][ei];

  s = off;
  for (int base = c0; base < c1; base += 8) {
    float v[8];
#pragma unroll
    for (int k = 0; k < 8; ++k) {
      const int cc = base + k;
      v[k] = (cc < c1) ? Z[(long)cc * 1024 + e] : 0.f;
    }
#pragma unroll
    for (int k = 0; k < 8; ++k) {
      const int cc = base + k;
      if (cc < c1) Z[(long)cc * 1024 + e] = s;  // in place: v read first
      s += v[k];
    }
  }
}

// ---------------- term: w = -(L v) ----------------------------------------
// Shuffle-based: stage -> reg x[16]; per-thread products vs sv=S[t];
// butterfly over 64 lanes (2 halves of 8); xl reused as scratch AFTER the
// reg preload barrier (red[16][16] + wvs at xl[256..]).
// S/Z1 alias one buffer: block c reads row c (sv) before writing row c.
template <bool LAST>
__global__ __launch_bounds__(1024, 4) void k_term(
    const float* __restrict__ At, const float* __restrict__ bvec,
    const float* __restrict__ gram, const float* __restrict__ S,
    float* __restrict__ Z1, float* __restrict__ acc, float* __restrict__ tvec,
    float* __restrict__ out) {
  __shared__ float xl[16384];  // 65,536 B EXACT
  const int c = blockIdx.x, t = threadIdx.x;
  const long i0 = (long)c * CC;
  const int wv = t >> 6, lane = t & 63;

  const float sv = S[(long)c * 1024 + t];  // coalesced, overlaps staging

  STAGE16(t);
  STAGE16(1024 + t);
  STAGE16(2048 + t);
  STAGE16(3072 + t);
  __syncthreads();

  float x[16];
#pragma unroll
  for (int j = 0; j < 16; ++j) x[j] = xl[(j << 10) | t];
  __syncthreads();  // xl now dead -> scratch

#pragma unroll
  for (int h = 0; h < 2; ++h) {
    float ph[8];
#pragma unroll
    for (int i = 0; i < 8; ++i) ph[i] = x[h * 8 + i] * sv;
#pragma unroll
    for (int off = 32; off >= 1; off >>= 1)
#pragma unroll
      for (int i = 0; i < 8; ++i) ph[i] += __shfl_xor(ph[i], off);
    if (lane == 0)
#pragma unroll
      for (int i = 0; i < 8; ++i) xl[(h * 8 + i) * 16 + wv] = ph[i];
  }
  __syncthreads();

  if (t < 16) {
    const int i = t;
    float dot = 0.f;
#pragma unroll
    for (int k = 0; k < 16; ++k) dot += xl[i * 16 + k];
    const float* grow = gram + (long)c * 120 + i * (i - 1) / 2;
    float g = 0.f;
#pragma unroll
    for (int j = 0; j < 15; ++j)
      if (j < i) g = fmaf(grow[j], LAST ? tvec[i0 + j] : acc[i0 + j], g);
    const float w = -ETA2 * (dot + g);
    if (LAST) {
      out[i0 + i] = fmaf(0.5f, acc[i0 + i] + w, bvec[i0 + i]);
    } else {
      tvec[i0 + i] = w;
      acc[i0 + i] += w;
      xl[256 + i] = w;
    }
  }
  if (!LAST) {
    __syncthreads();
    float z = 0.f;
#pragma unroll
    for (int j = 0; j < 16; ++j) z = fmaf(xl[256 + j], x[j], z);
    Z1[(long)c * 1024 + t] = z;
  }
}

extern "C" void kernel_launch(void* const* d_in, const int* in_sizes, int n_in,
                              void* d_out, int out_size, void* d_ws,
                              size_t ws_size, hipStream_t stream) {
  const float* At = (const float*)d_in[0];  // (1024, 20000) row-major
  const float* b  = (const float*)d_in[1];
  const float* w1 = (const float*)d_in[2];
  const float* W2 = (const float*)d_in[3];  // (512, 1023) row-major
  float* out = (float*)d_out;
  float* ws = (float*)d_ws;

  float* gram  = ws + OFF_GRAM;
  float* Zsh   = ws + OFF_Z;  // Zr -> S1 -> Z1 -> S2 (single buffer)
  float* scalp = ws + OFF_SCLP;
  float* acc   = ws + OFF_ACC;
  float* tvec  = ws + OFF_TV;
  float* x0ws  = ws + OFF_X0;

  k_init<<<dim3(53), dim3(1024), 0, stream>>>(At, b, w1, W2, out, scalp, x0ws);
  k_gram<<<dim3(NCH), dim3(1024), 0, stream>>>(At, b, x0ws, gram, Zsh, scalp,
                                               acc);
  k_scan<<<dim3(32), dim3(1024), 0, stream>>>(Zsh);
  k_term<false><<<dim3(NCH), dim3(1024), 0, stream>>>(At, b, gram, Zsh, Zsh,
                                                      acc, tvec, out);
  k_scan<<<dim3(32), dim3(1024), 0, stream>>>(Zsh);
  k_term<true><<<dim3(NCH), dim3(1024), 0, stream>>>(At, b, gram, Zsh, Zsh,
                                                     acc, tvec, out);
}